// Round 13
// baseline (677.007 us; speedup 1.0000x reference)
//
#include <hip/hip_runtime.h>
#include <cstdint>
#include <cstddef>

// N=100000, E=20000, P=1600000, din=128, dh=64, H=4, DCAT=512, C=40
static constexpr int DIN = 128;
static constexpr int DH = 64;
static constexpr int NH = 4;
static constexpr int DCAT = 512;
static constexpr int NC = 40;
static constexpr int E_CONST = 20000;
static constexpr int SH_V = 9, SUBD_V = 512;
static constexpr int SH_E = 7, SUBD_E = 128;
static constexpr int ECH = 11, NSUB_E = 10;
static constexpr int VCH = 12, NSUB_V = 25;
static constexpr int CHUNKA = 4096;
static constexpr int DCH = 2048;   // elements per degree-sort block

typedef unsigned short u16;
typedef __attribute__((ext_vector_type(4))) unsigned short u16x4;
typedef __attribute__((ext_vector_type(8))) unsigned short u16x8;
typedef __attribute__((ext_vector_type(8))) short bf16x8;
typedef __attribute__((ext_vector_type(4))) float f32x4;

static __device__ __forceinline__ float bf2f(u16 u) {
    union { unsigned int i; float f; } x;
    x.i = ((unsigned int)u) << 16;
    return x.f;
}
static __device__ __forceinline__ u16 f2bf(float f) {
    union { float f; unsigned int i; } x;
    x.f = f;
    unsigned int r = x.i + 0x7fffu + ((x.i >> 16) & 1u);
    return (u16)(r >> 16);
}

// ---------------- CSR build ----------------

__global__ void k_hist2(const int* __restrict__ pv, const int* __restrict__ pe,
                        int* __restrict__ btot_v, int* __restrict__ btot_e, int P) {
    __shared__ int cv[256], ce[256];
    int tid = threadIdx.x;
    cv[tid] = 0; ce[tid] = 0;
    __syncthreads();
    int p0 = blockIdx.x * CHUNKA;
    #pragma unroll
    for (int j = 0; j < CHUNKA / 256; ++j) {
        int p = p0 + tid + j * 256;
        if (p < P) {
            atomicAdd(&cv[pv[p] >> SH_V], 1);
            atomicAdd(&ce[pe[p] >> SH_E], 1);
        }
    }
    __syncthreads();
    if (cv[tid]) atomicAdd(&btot_v[tid], cv[tid]);
    if (ce[tid]) atomicAdd(&btot_e[tid], ce[tid]);
}

static __device__ void scan_body(int* a, int n) {
    __shared__ int wsum[16];
    __shared__ int carry_s;
    int tid = threadIdx.x;
    int lane = tid & 63;
    int w = tid >> 6;
    if (tid == 0) carry_s = 0;
    __syncthreads();
    for (int base = 0; base < n; base += 1024) {
        int i = base + tid;
        int v = (i < n) ? a[i] : 0;
        int x = v;
        #pragma unroll
        for (int off = 1; off < 64; off <<= 1) {
            int t = __shfl_up(x, off);
            if (lane >= off) x += t;
        }
        if (lane == 63) wsum[w] = x;
        __syncthreads();
        int woff = 0;
        for (int k = 0; k < w; ++k) woff += wsum[k];
        int carry = carry_s;
        if (i < n) a[i] = carry + woff + x - v;
        int tot = 0;
        for (int k = 0; k < 16; ++k) tot += wsum[k];
        __syncthreads();
        if (tid == 0) carry_s = carry + tot;
        __syncthreads();
    }
    if (tid == 0) a[n] = carry_s;
}

__global__ void k_scan_both(int* __restrict__ a, int na, int* __restrict__ b, int nb) {
    if (blockIdx.x == 0) scan_body(a, na);
    else scan_body(b, nb);
}

__global__ void k_scatter2way(const int* __restrict__ pv, const int* __restrict__ pe,
                              const int* __restrict__ bstart_v, const int* __restrict__ bstart_e,
                              int* __restrict__ cur_v, int* __restrict__ cur_e,
                              uint2* __restrict__ sorted_v, uint2* __restrict__ sorted_e, int P) {
    __shared__ int cv[256], ce[256], posv[256], pose[256];
    int tid = threadIdx.x;
    cv[tid] = 0; ce[tid] = 0;
    __syncthreads();
    int p0 = blockIdx.x * CHUNKA;
    int kv[CHUNKA / 256], ke[CHUNKA / 256];
    #pragma unroll
    for (int j = 0; j < CHUNKA / 256; ++j) {
        int p = p0 + tid + j * 256;
        if (p < P) {
            kv[j] = pv[p];
            ke[j] = pe[p];
            atomicAdd(&cv[kv[j] >> SH_V], 1);
            atomicAdd(&ce[ke[j] >> SH_E], 1);
        } else {
            kv[j] = -1;
            ke[j] = -1;
        }
    }
    __syncthreads();
    if (cv[tid]) posv[tid] = bstart_v[tid] + atomicAdd(&cur_v[tid], cv[tid]);
    if (ce[tid]) pose[tid] = bstart_e[tid] + atomicAdd(&cur_e[tid], ce[tid]);
    __syncthreads();
    #pragma unroll
    for (int j = 0; j < CHUNKA / 256; ++j) {
        if (kv[j] >= 0) {
            int iv = atomicAdd(&posv[kv[j] >> SH_V], 1);
            sorted_v[iv] = make_uint2((unsigned)kv[j], (unsigned)ke[j]);
            int ie = atomicAdd(&pose[ke[j] >> SH_E], 1);
            sorted_e[ie] = make_uint2((unsigned)ke[j], (unsigned)kv[j]);
        }
    }
}

template <int SUBD, int SH, int NSUB, int CSH>
__global__ __launch_bounds__(256) void k_build_ord(const uint2* __restrict__ sorted,
                                                   const int* __restrict__ bstart,
                                                   int* __restrict__ start_out,
                                                   int* __restrict__ deg_out,
                                                   int* __restrict__ csr_out, int D) {
    constexpr int NK2 = SUBD * NSUB;
    constexpr int STRIP = (NK2 + 255) / 256;
    __shared__ int cnt[NK2];
    __shared__ int wsum[4];
    int b = blockIdx.x;
    int tid = threadIdx.x;
    int base_key = b << SH;
    int s0 = bstart[b];
    int cntN = bstart[b + 1] - s0;
    for (int k = tid; k < NK2; k += 256) cnt[k] = 0;
    __syncthreads();
    for (int i = tid; i < cntN; i += 256) {
        uint2 pr = sorted[s0 + i];
        int k2 = ((int)pr.x - base_key) * NSUB + ((int)pr.y >> CSH);
        atomicAdd(&cnt[k2], 1);
    }
    __syncthreads();
    int local[STRIP];
    int sum = 0;
    int t0 = tid * STRIP;
    #pragma unroll
    for (int j = 0; j < STRIP; ++j) {
        int idx = t0 + j;
        local[j] = (idx < NK2) ? cnt[idx] : 0;
        sum += local[j];
    }
    int lane = tid & 63, w = tid >> 6;
    int x = sum;
    #pragma unroll
    for (int off = 1; off < 64; off <<= 1) {
        int t = __shfl_up(x, off);
        if (lane >= off) x += t;
    }
    if (lane == 63) wsum[w] = x;
    __syncthreads();
    int woff = 0;
    for (int k = 0; k < w; ++k) woff += wsum[k];
    int run = woff + x - sum;
    __syncthreads();
    #pragma unroll
    for (int j = 0; j < STRIP; ++j) {
        int idx = t0 + j;
        if (idx < NK2) {
            int tmp = local[j];
            cnt[idx] = run;
            run += tmp;
        }
    }
    __syncthreads();
    for (int loc = tid; loc < SUBD; loc += 256) {
        int key = base_key + loc;
        if (key < D) {
            int st = cnt[loc * NSUB];
            int en = (loc == SUBD - 1) ? cntN : cnt[(loc + 1) * NSUB];
            start_out[key] = s0 + st;
            deg_out[key] = en - st;
        }
    }
    __syncthreads();
    for (int i = tid; i < cntN; i += 256) {
        uint2 pr = sorted[s0 + i];
        int k2 = ((int)pr.x - base_key) * NSUB + ((int)pr.y >> CSH);
        int idx = atomicAdd(&cnt[k2], 1);
        csr_out[s0 + idx] = (int)pr.y;
    }
}

// ---------------- degree counting sort (perm arrays for divergence-free grouping) ----------------

__global__ void k_deg_hist(const int* __restrict__ deg, int n, int* __restrict__ btot) {
    __shared__ int h[1024];
    int tid = threadIdx.x;
    for (int k = tid; k < 1024; k += 256) h[k] = 0;
    __syncthreads();
    int base = blockIdx.x * DCH;
    int end = base + DCH < n ? base + DCH : n;
    for (int i = base + tid; i < end; i += 256) {
        int d = deg[i];
        atomicAdd(&h[d < 1023 ? d : 1023], 1);
    }
    __syncthreads();
    for (int k = tid; k < 1024; k += 256)
        if (h[k]) atomicAdd(&btot[k], h[k]);
}

__global__ void k_deg_scatter(const int* __restrict__ deg, int n,
                              const int* __restrict__ bstart, int* __restrict__ cur,
                              int* __restrict__ perm) {
    __shared__ int h[1024], pos[1024];
    int tid = threadIdx.x;
    for (int k = tid; k < 1024; k += 256) h[k] = 0;
    __syncthreads();
    int base = blockIdx.x * DCH;
    int end = base + DCH < n ? base + DCH : n;
    for (int i = base + tid; i < end; i += 256) {
        int d = deg[i];
        atomicAdd(&h[d < 1023 ? d : 1023], 1);
    }
    __syncthreads();
    for (int k = tid; k < 1024; k += 256)
        if (h[k]) pos[k] = bstart[k] + atomicAdd(&cur[k], h[k]);
    __syncthreads();
    for (int i = base + tid; i < end; i += 256) {
        int d = deg[i];
        int b = d < 1023 ? d : 1023;
        int p = atomicAdd(&pos[b], 1);
        perm[p] = i;
    }
}

// ---------------- fused weight prep ----------------
__global__ void k_prep(const float* __restrict__ W1, const float* __restrict__ b1,
                       const float* __restrict__ av1, const float* __restrict__ W2,
                       float* __restrict__ wav, float* __restrict__ bav,
                       u16* __restrict__ WcatT, u16* __restrict__ W2T) {
    int bid = blockIdx.x;
    int tid = threadIdx.x;
    if (bid < 4) {
        int h = bid;
        if (tid < DIN) {
            float s = 0.f;
            for (int j = 0; j < DH; ++j)
                s += W1[(size_t)(h * DIN + tid) * DH + j] * av1[h * DH + j];
            wav[h * DIN + tid] = s;
        }
        if (tid == 0) {
            float t = 0.f;
            for (int j = 0; j < DH; ++j) t += b1[h * DH + j] * av1[h * DH + j];
            bav[h] = t;
        }
    } else if (bid < 4 + 128) {
        int idx = (bid - 4) * 256 + tid;
        int c = idx >> 7, k = idx & 127;
        int h = c >> 6, j = c & 63;
        WcatT[c * DIN + k] = f2bf(W1[((size_t)h * DIN + k) * DH + j]);
    } else {
        int idx = (bid - 132) * 256 + tid;
        int c = idx >> 9, k = idx & 511;
        float v = (c < NC) ? W2[(size_t)k * NC + c] : 0.f;
        W2T[c * DCAT + k] = f2bf(v);
    }
}

// ---------------- conversion + node attention term ----------------
__global__ void k_conv(const float* __restrict__ X0, const float* __restrict__ X1,
                       const float* __restrict__ wav, const float* __restrict__ bav,
                       u16* __restrict__ Xbi, float* __restrict__ sv8, int N) {
    int wave = (blockIdx.x * blockDim.x + threadIdx.x) >> 6;
    int lane = threadIdx.x & 63;
    if (wave >= N) return;
    int xz = blockIdx.y;
    const float* X = xz ? X1 : X0;
    float2 a = *(const float2*)(X + (size_t)wave * DIN + lane * 2);
    unsigned int packed = (unsigned int)f2bf(a.x) | ((unsigned int)f2bf(a.y) << 16);
    *(unsigned int*)(Xbi + (size_t)wave * 256 + xz * 128 + lane * 2) = packed;
    float s[NH];
    #pragma unroll
    for (int h = 0; h < NH; ++h) {
        float2 wv = *(const float2*)(wav + h * DIN + lane * 2);
        float t = a.x * wv.x + a.y * wv.y;
        #pragma unroll
        for (int off = 32; off >= 1; off >>= 1) t += __shfl_xor(t, off);
        s[h] = t;
    }
    if (lane == 0) {
        #pragma unroll
        for (int h = 0; h < NH; ++h) sv8[(size_t)(xz * 4 + h) * N + wave] = s[h] + bav[h];
    }
}

// ---------------- edge mean (layer 1) ----------------
__global__ void k_edge_mean1(const u16* __restrict__ Xbi, const int* __restrict__ start_e,
                             const int* __restrict__ deg_e, const int* __restrict__ csr_e_v,
                             u16* __restrict__ Xbar0, u16* __restrict__ Xbar1, int E) {
    int wave = (blockIdx.x * blockDim.x + threadIdx.x) >> 6;
    int lane = threadIdx.x & 63;
    if (wave >= E) return;
    int s = start_e[wave], t = s + deg_e[wave];
    int q = lane >> 4, c = lane & 15;
    float a0[8], a1[8];
    #pragma unroll
    for (int j = 0; j < 8; ++j) { a0[j] = 0.f; a1[j] = 0.f; }
    int i = s + q;
    u16x8 y0A = {0}, y1A = {0}, y0B = {0}, y1B = {0}, y0C = {0}, y1C = {0};
#define EM1_LOAD(Y0, Y1, IDX) { int v_ = csr_e_v[IDX]; \
        const u16* yp_ = Xbi + (size_t)v_ * 256 + c * 8; \
        Y0 = *(const u16x8*)yp_; Y1 = *(const u16x8*)(yp_ + 128); }
#define EM1_CONSUME(Y0, Y1) { \
        _Pragma("unroll") \
        for (int j = 0; j < 8; ++j) { a0[j] += bf2f(Y0[j]); a1[j] += bf2f(Y1[j]); } }
    if (i < t) EM1_LOAD(y0A, y1A, i);
    if (i + 4 < t) EM1_LOAD(y0B, y1B, i + 4);
    if (i + 8 < t) EM1_LOAD(y0C, y1C, i + 8);
    for (; i + 8 < t; i += 12) {
        EM1_CONSUME(y0A, y1A);
        if (i + 12 < t) EM1_LOAD(y0A, y1A, i + 12);
        EM1_CONSUME(y0B, y1B);
        if (i + 16 < t) EM1_LOAD(y0B, y1B, i + 16);
        EM1_CONSUME(y0C, y1C);
        if (i + 20 < t) EM1_LOAD(y0C, y1C, i + 20);
    }
    if (i < t) EM1_CONSUME(y0A, y1A);
    if (i + 4 < t) EM1_CONSUME(y0B, y1B);
#undef EM1_LOAD
#undef EM1_CONSUME
    #pragma unroll
    for (int j = 0; j < 8; ++j) {
        a0[j] += __shfl_xor(a0[j], 16);
        a0[j] += __shfl_xor(a0[j], 32);
        a1[j] += __shfl_xor(a1[j], 16);
        a1[j] += __shfl_xor(a1[j], 32);
    }
    int deg = t - s;
    float inv = 1.f / (float)(deg > 1 ? deg : 1);
    if (q == 0) {
        u16x8 r0, r1;
        #pragma unroll
        for (int j = 0; j < 8; ++j) { r0[j] = f2bf(a0[j] * inv); r1[j] = f2bf(a1[j] * inv); }
        *(u16x8*)(Xbar0 + (size_t)wave * DIN + c * 8) = r0;
        *(u16x8*)(Xbar1 + (size_t)wave * DIN + c * 8) = r1;
    }
}

// ---------------- MFMA GEMM with fused row-dot epilogue ----------------
template <int KDIM, int NTILES, int DOTMODE>
__global__ __launch_bounds__(256) void k_gemm_mfma(const u16* __restrict__ A0,
                                                   const u16* __restrict__ A1, int M,
                                                   const u16* __restrict__ Bt,
                                                   const float* __restrict__ bias,
                                                   u16* __restrict__ out0, u16* __restrict__ out1,
                                                   int ldo, int ncols,
                                                   const float* __restrict__ dvec,
                                                   float* __restrict__ dout) {
    constexpr int LDB = KDIM + 8;
    __shared__ u16 Bs[NTILES * 16 * LDB];
    const u16* A = blockIdx.z ? A1 : A0;
    u16* out = blockIdx.z ? out1 : out0;
    int tid = threadIdx.x;
    int colbase = blockIdx.y * NTILES * 16;
    const u16* Btblk = Bt + (size_t)colbase * KDIM;
    for (int idx = tid * 4; idx < NTILES * 16 * KDIM; idx += 256 * 4) {
        int c = idx / KDIM, k = idx % KDIM;
        *(u16x4*)&Bs[c * LDB + k] = *(const u16x4*)(Btblk + c * KDIM + k);
    }
    __syncthreads();
    int w = tid >> 6, lane = tid & 63;
    int r0 = blockIdx.x * 64 + w * 16;
    int arow = r0 + (lane & 15);
    bool avalid = arow < M;
    const u16* ap = A + (size_t)arow * KDIM + (lane >> 4) * 8;
    f32x4 acc[NTILES];
    #pragma unroll
    for (int nt = 0; nt < NTILES; ++nt) acc[nt] = (f32x4){0.f, 0.f, 0.f, 0.f};
    #pragma unroll
    for (int k0 = 0; k0 < KDIM; k0 += 32) {
        bf16x8 a = (bf16x8)(short)0;
        if (avalid) a = *(const bf16x8*)(ap + k0);
        #pragma unroll
        for (int nt = 0; nt < NTILES; ++nt) {
            bf16x8 b = *(const bf16x8*)&Bs[(nt * 16 + (lane & 15)) * LDB + k0 + (lane >> 4) * 8];
            acc[nt] = __builtin_amdgcn_mfma_f32_16x16x32_bf16(a, b, acc[nt], 0, 0, 0);
        }
    }
    #pragma unroll
    for (int j = 0; j < 4; ++j) {
        int row = r0 + (lane >> 4) * 4 + j;
        float pA = 0.f, pB = 0.f;
        #pragma unroll
        for (int nt = 0; nt < NTILES; ++nt) {
            int col = colbase + nt * 16 + (lane & 15);
            bool cok = col < ncols;
            float val = cok ? acc[nt][j] + bias[col] : 0.f;
            if (DOTMODE == 1) {
                float dv = dvec[col];
                if (nt < NTILES / 2) pA += val * dv; else pB += val * dv;
            } else if (DOTMODE == 2) {
                pA += cok ? val * dvec[col] : 0.f;
            }
            if (row < M && cok) out[(size_t)row * ldo + col] = f2bf(val);
        }
        if (DOTMODE) {
            pA += __shfl_xor(pA, 1);
            pA += __shfl_xor(pA, 2);
            pA += __shfl_xor(pA, 4);
            pA += __shfl_xor(pA, 8);
            if (DOTMODE == 1) {
                pB += __shfl_xor(pB, 1);
                pB += __shfl_xor(pB, 2);
                pB += __shfl_xor(pB, 4);
                pB += __shfl_xor(pB, 8);
            }
            if ((lane & 15) == 0 && row < M) {
                if (DOTMODE == 1) {
                    int hbase = blockIdx.y * 2;
                    int z = blockIdx.z;
                    dout[(size_t)(z * 4 + hbase) * M + row] = pA;
                    dout[(size_t)(z * 4 + hbase + 1) * M + row] = pB;
                } else {
                    dout[row] = pA;
                }
            }
        }
    }
}

// ---------------- node pass (layer 1): XCD-sliced, group-per-node (degree-sorted), 2-slot pipeline ----------------
__global__ void k_node_pass1(const u16* __restrict__ Ycat, const float* __restrict__ se8,
                             const float* __restrict__ sv8, const int* __restrict__ start_v,
                             const int* __restrict__ deg_v, const int* __restrict__ csr_v_e,
                             const int* __restrict__ perm, u16* __restrict__ hbuf,
                             int N, int E) {
    int bid = blockIdx.x;
    int s = bid & 7;
    int warp = threadIdx.x >> 6;
    int lane = threadIdx.x & 63;
    int g = lane >> 3, c = lane & 7;
    int gidx = (bid >> 3) * 32 + warp * 8 + g;
    if (gidx >= N) return;
    int node = perm[gidx];   // degree-sorted: groups in a wave get near-equal degrees
    int p0 = start_v[node];
    int p1 = p0 + deg_v[node];
    float sv = sv8[(size_t)s * N + node];
    const float* seS = se8 + (size_t)s * E;
    const u16* ybase = Ycat + s * 64 + c * 8;
    float den = 0.f;
    float acc[8];
    #pragma unroll
    for (int j = 0; j < 8; ++j) acc[j] = 0.f;
    float sA = 0.f, sB = 0.f;
    u16x8 yA = {0}, yB = {0};
#define NP1_LOAD(S, Y, IDX) { int e_ = csr_v_e[IDX]; S = seS[e_]; \
        Y = *(const u16x8*)(ybase + (size_t)e_ * 512); }
#define NP1_CONSUME(S, Y) { \
        float x_ = S + sv; x_ = fmaxf(x_, 0.2f * x_); float ex_ = __expf(x_); \
        den += ex_; \
        _Pragma("unroll") \
        for (int j = 0; j < 8; ++j) acc[j] += ex_ * bf2f(Y[j]); }
    int i = p0;
    if (i < p1) NP1_LOAD(sA, yA, i);
    if (i + 1 < p1) NP1_LOAD(sB, yB, i + 1);
    for (; i + 1 < p1; i += 2) {
        NP1_CONSUME(sA, yA);
        if (i + 2 < p1) NP1_LOAD(sA, yA, i + 2);
        NP1_CONSUME(sB, yB);
        if (i + 3 < p1) NP1_LOAD(sB, yB, i + 3);
    }
    if (i < p1) NP1_CONSUME(sA, yA);
#undef NP1_LOAD
#undef NP1_CONSUME
    float inv = (p1 > p0) ? 1.f / den : 0.f;
    u16x8 r;
    #pragma unroll
    for (int j = 0; j < 8; ++j) {
        float o = acc[j] * inv;
        o = o > 0.f ? o : __expf(o) - 1.f;
        r[j] = f2bf(o);
    }
    *(u16x8*)(hbuf + (size_t)node * DCAT + s * 64 + c * 8) = r;
}

// ---------------- layer 2: group-per-segment, degree-sorted ----------------

__global__ void k_edge_mean2(const u16* __restrict__ Xp2b, const int* __restrict__ start_e,
                             const int* __restrict__ deg_ea, const int* __restrict__ csr_e_v,
                             const int* __restrict__ perm, u16* __restrict__ Y2b,
                             const float* __restrict__ ae2, float* __restrict__ se2, int E) {
    int warp = threadIdx.x >> 6;
    int lane = threadIdx.x & 63;
    int g = lane >> 3, c = lane & 7;
    int gidx = blockIdx.x * 32 + warp * 8 + g;
    if (gidx >= E) return;
    int edge = perm[gidx];
    int p0 = start_e[edge], p1 = p0 + deg_ea[edge];
    bool act = c < 5;
    const u16* xbase = Xp2b + c * 8;
    float acc[8];
    #pragma unroll
    for (int j = 0; j < 8; ++j) acc[j] = 0.f;
    if (act) {
        for (int i = p0; i < p1; ++i) {
            int v = csr_e_v[i];
            u16x8 y = *(const u16x8*)(xbase + (size_t)v * NC);
            #pragma unroll
            for (int j = 0; j < 8; ++j) acc[j] += bf2f(y[j]);
        }
    }
    int deg = p1 - p0;
    float inv = 1.f / (float)(deg > 1 ? deg : 1);
    float p = 0.f;
    if (act) {
        u16x8 r;
        #pragma unroll
        for (int j = 0; j < 8; ++j) {
            float y = acc[j] * inv;
            p += y * ae2[c * 8 + j];
            r[j] = f2bf(y);
        }
        *(u16x8*)(Y2b + (size_t)edge * NC + c * 8) = r;
    }
    p += __shfl_xor(p, 1);
    p += __shfl_xor(p, 2);
    p += __shfl_xor(p, 4);
    if (c == 0) se2[edge] = p;
}

__global__ void k_node_pass2(const u16* __restrict__ Y2b, const float* __restrict__ se2,
                             const float* __restrict__ sv2, const int* __restrict__ start_v,
                             const int* __restrict__ deg_va, const int* __restrict__ csr_v_e,
                             const int* __restrict__ perm, float* __restrict__ out, int N) {
    int warp = threadIdx.x >> 6;
    int lane = threadIdx.x & 63;
    int g = lane >> 3, c = lane & 7;
    int gidx = blockIdx.x * 32 + warp * 8 + g;
    if (gidx >= N) return;
    int node = perm[gidx];
    int p0 = start_v[node], p1 = p0 + deg_va[node];
    bool act = c < 5;
    float* orow = out + (size_t)node * NC;
    if (p1 == p0) {
        if (act) {
            *(float4*)(orow + c * 8) = make_float4(0.f, 0.f, 0.f, 0.f);
            *(float4*)(orow + c * 8 + 4) = make_float4(0.f, 0.f, 0.f, 0.f);
        }
        return;
    }
    float svv = sv2[node];
    const u16* ybase = Y2b + c * 8;
    float den = 0.f;
    float acc[8];
    #pragma unroll
    for (int j = 0; j < 8; ++j) acc[j] = 0.f;
    for (int i = p0; i < p1; ++i) {
        int e = csr_v_e[i];
        float x = se2[e] + svv;
        x = fmaxf(x, 0.2f * x);
        float ex = __expf(x);
        den += ex;
        if (act) {
            u16x8 y = *(const u16x8*)(ybase + (size_t)e * NC);
            #pragma unroll
            for (int j = 0; j < 8; ++j) acc[j] += ex * bf2f(y[j]);
        }
    }
    if (act) {
        float inv = 1.f / den;
        float o[8];
        #pragma unroll
        for (int j = 0; j < 8; ++j) {
            float v = acc[j] * inv;
            o[j] = v > 0.f ? v : __expf(v) - 1.f;
        }
        *(float4*)(orow + c * 8) = make_float4(o[0], o[1], o[2], o[3]);
        *(float4*)(orow + c * 8 + 4) = make_float4(o[4], o[5], o[6], o[7]);
    }
}

// ---------------- launcher ----------------
extern "C" void kernel_launch(void* const* d_in, const int* in_sizes, int n_in,
                              void* d_out, int out_size, void* d_ws, size_t ws_size,
                              hipStream_t stream) {
    const float* x0 = (const float*)d_in[0];
    const float* x1 = (const float*)d_in[1];
    const float* W1 = (const float*)d_in[2];
    const float* b1 = (const float*)d_in[3];
    const float* ae1 = (const float*)d_in[4];
    const float* av1 = (const float*)d_in[5];
    const float* W2 = (const float*)d_in[6];
    const float* b2 = (const float*)d_in[7];
    const float* ae2 = (const float*)d_in[8];
    const float* av2 = (const float*)d_in[9];
    const int* pe = (const int*)d_in[10];
    const int* pv = (const int*)d_in[11];

    const int N = in_sizes[0] / DIN;  // 100000
    const int P = in_sizes[10];       // 1600000
    const int E = E_CONST;            // 20000
    const int NBKT_V = (N + SUBD_V - 1) / SUBD_V;   // 196
    const int NBKT_E = (E + SUBD_E - 1) / SUBD_E;   // 157

    char* base = (char*)d_ws;
    auto alloc = [&](size_t bytes) -> void* {
        void* p = (void*)base;
        base += (bytes + 255) & ~(size_t)255;
        return p;
    };
    u16* Xbi = (u16*)alloc((size_t)N * 256 * 2);
    u16* hbuf = (u16*)alloc((size_t)N * DCAT * 2);
    u16* Xbar0 = (u16*)alloc((size_t)E * DIN * 2);
    u16* Xbar1 = (u16*)alloc((size_t)E * DIN * 2);
    u16* Ycat = (u16*)alloc((size_t)E * 512 * 2);
    u16* Xp2b = (u16*)alloc((size_t)N * NC * 2);
    u16* Y2b = (u16*)alloc((size_t)E * NC * 2);
    float* se8 = (float*)alloc((size_t)8 * E * 4);
    float* se2 = (float*)alloc((size_t)E * 4);
    float* sv8 = (float*)alloc((size_t)8 * N * 4);
    float* sv2 = (float*)alloc((size_t)N * 4);
    float* wav = (float*)alloc((size_t)NH * DIN * 4);
    float* bav = (float*)alloc((size_t)NH * 4);
    u16* WcatT = (u16*)alloc((size_t)256 * DIN * 2);
    u16* W2T = (u16*)alloc((size_t)48 * DCAT * 2);
    uint2* sorted_v = (uint2*)alloc((size_t)P * 8);
    uint2* sorted_e = (uint2*)alloc((size_t)P * 8);
    int* start_v = (int*)alloc((size_t)N * 4);
    int* deg_v = (int*)alloc((size_t)N * 4);
    int* start_e = (int*)alloc((size_t)E * 4);
    int* deg_e = (int*)alloc((size_t)E * 4);
    int* csr_v_e = (int*)alloc((size_t)P * 4);
    int* csr_e_v = (int*)alloc((size_t)P * 4);
    int* perm_v = (int*)alloc((size_t)N * 4);
    int* perm_e = (int*)alloc((size_t)E * 4);
    char* zstart = base;
    int* bstart_v = (int*)alloc((size_t)(NBKT_V + 1) * 4);
    int* bstart_e = (int*)alloc((size_t)(NBKT_E + 1) * 4);
    int* cur_v = (int*)alloc((size_t)256 * 4);
    int* cur_e = (int*)alloc((size_t)256 * 4);
    int* dhist_v = (int*)alloc((size_t)1025 * 4);
    int* dhist_e = (int*)alloc((size_t)1025 * 4);
    int* dcur_v = (int*)alloc((size_t)1024 * 4);
    int* dcur_e = (int*)alloc((size_t)1024 * 4);
    size_t zbytes = (size_t)(base - zstart);

    if ((size_t)(base - (char*)d_ws) > ws_size) return;

    hipMemsetAsync(zstart, 0, zbytes, stream);

    dim3 b256(256);
    int nA = (P + CHUNKA - 1) / CHUNKA;   // 391
    k_hist2<<<nA, b256, 0, stream>>>(pv, pe, bstart_v, bstart_e, P);
    k_scan_both<<<2, 1024, 0, stream>>>(bstart_v, NBKT_V, bstart_e, NBKT_E);
    k_scatter2way<<<nA, b256, 0, stream>>>(pv, pe, bstart_v, bstart_e, cur_v, cur_e,
                                           sorted_v, sorted_e, P);
    k_build_ord<SUBD_V, SH_V, NSUB_E, ECH><<<NBKT_V, b256, 0, stream>>>(sorted_v, bstart_v,
                                                                        start_v, deg_v,
                                                                        csr_v_e, N);
    k_build_ord<SUBD_E, SH_E, NSUB_V, VCH><<<NBKT_E, b256, 0, stream>>>(sorted_e, bstart_e,
                                                                        start_e, deg_e,
                                                                        csr_e_v, E);

    // degree counting sort -> perm_v, perm_e
    int nDV = (N + DCH - 1) / DCH;   // 49
    int nDE = (E + DCH - 1) / DCH;   // 10
    k_deg_hist<<<nDV, b256, 0, stream>>>(deg_v, N, dhist_v);
    k_deg_hist<<<nDE, b256, 0, stream>>>(deg_e, E, dhist_e);
    k_scan_both<<<2, 1024, 0, stream>>>(dhist_v, 1024, dhist_e, 1024);
    k_deg_scatter<<<nDV, b256, 0, stream>>>(deg_v, N, dhist_v, dcur_v, perm_v);
    k_deg_scatter<<<nDE, b256, 0, stream>>>(deg_e, E, dhist_e, dcur_e, perm_e);

    k_prep<<<228, b256, 0, stream>>>(W1, b1, av1, W2, wav, bav, WcatT, W2T);

    int gN4 = (N + 3) / 4;
    int gE4 = (E + 3) / 4;
    dim3 gconv(gN4, 2);
    k_conv<<<gconv, b256, 0, stream>>>(x0, x1, wav, bav, Xbi, sv8, N);

    k_edge_mean1<<<gE4, b256, 0, stream>>>(Xbi, start_e, deg_e, csr_e_v, Xbar0, Xbar1, E);
    dim3 g1((E + 63) / 64, 2, 2);
    k_gemm_mfma<DIN, 8, 1><<<g1, b256, 0, stream>>>(Xbar0, Xbar1, E, WcatT, b1,
                                                    Ycat, Ycat + 256, 512, 256, ae1, se8);
    int gnp1 = ((N + 31) / 32) * 8;
    k_node_pass1<<<gnp1, b256, 0, stream>>>(Ycat, se8, sv8, start_v, deg_v, csr_v_e,
                                            perm_v, hbuf, N, E);

    dim3 g2((N + 63) / 64, 1, 1);
    k_gemm_mfma<DCAT, 3, 2><<<g2, b256, 0, stream>>>(hbuf, hbuf, N, W2T, b2, Xp2b, Xp2b,
                                                     NC, NC, av2, sv2);
    int gseg = (E + 31) / 32;
    k_edge_mean2<<<gseg, b256, 0, stream>>>(Xp2b, start_e, deg_e, csr_e_v, perm_e,
                                            Y2b, ae2, se2, E);
    int gnp2 = (N + 31) / 32;
    k_node_pass2<<<gnp2, b256, 0, stream>>>(Y2b, se2, sv2, start_v, deg_v, csr_v_e,
                                            perm_v, (float*)d_out, N);
}

// Round 14
// 621.884 us; speedup vs baseline: 1.0886x; 1.0886x over previous
//
#include <hip/hip_runtime.h>
#include <cstdint>
#include <cstddef>

// N=100000, E=20000, P=1600000, din=128, dh=64, H=4, DCAT=512, C=40
static constexpr int DIN = 128;
static constexpr int DH = 64;
static constexpr int NH = 4;
static constexpr int DCAT = 512;
static constexpr int NC = 40;
static constexpr int E_CONST = 20000;
static constexpr int SH_V = 9, SUBD_V = 512;
static constexpr int SH_E = 7, SUBD_E = 128;
static constexpr int ECH = 11, NSUB_E = 10;
static constexpr int VCH = 12, NSUB_V = 25;
static constexpr int CHUNKA = 4096;

typedef unsigned short u16;
typedef __attribute__((ext_vector_type(4))) unsigned short u16x4;
typedef __attribute__((ext_vector_type(8))) unsigned short u16x8;
typedef __attribute__((ext_vector_type(8))) short bf16x8;
typedef __attribute__((ext_vector_type(4))) float f32x4;

static __device__ __forceinline__ float bf2f(u16 u) {
    union { unsigned int i; float f; } x;
    x.i = ((unsigned int)u) << 16;
    return x.f;
}
static __device__ __forceinline__ u16 f2bf(float f) {
    union { float f; unsigned int i; } x;
    x.f = f;
    unsigned int r = x.i + 0x7fffu + ((x.i >> 16) & 1u);
    return (u16)(r >> 16);
}

// ---------------- CSR build ----------------

__global__ void k_hist2(const int* __restrict__ pv, const int* __restrict__ pe,
                        int* __restrict__ btot_v, int* __restrict__ btot_e, int P) {
    __shared__ int cv[256], ce[256];
    int tid = threadIdx.x;
    cv[tid] = 0; ce[tid] = 0;
    __syncthreads();
    int p0 = blockIdx.x * CHUNKA;
    #pragma unroll
    for (int j = 0; j < CHUNKA / 256; ++j) {
        int p = p0 + tid + j * 256;
        if (p < P) {
            atomicAdd(&cv[pv[p] >> SH_V], 1);
            atomicAdd(&ce[pe[p] >> SH_E], 1);
        }
    }
    __syncthreads();
    if (cv[tid]) atomicAdd(&btot_v[tid], cv[tid]);
    if (ce[tid]) atomicAdd(&btot_e[tid], ce[tid]);
}

static __device__ void scan_body(int* a, int n) {
    __shared__ int wsum[16];
    __shared__ int carry_s;
    int tid = threadIdx.x;
    int lane = tid & 63;
    int w = tid >> 6;
    if (tid == 0) carry_s = 0;
    __syncthreads();
    for (int base = 0; base < n; base += 1024) {
        int i = base + tid;
        int v = (i < n) ? a[i] : 0;
        int x = v;
        #pragma unroll
        for (int off = 1; off < 64; off <<= 1) {
            int t = __shfl_up(x, off);
            if (lane >= off) x += t;
        }
        if (lane == 63) wsum[w] = x;
        __syncthreads();
        int woff = 0;
        for (int k = 0; k < w; ++k) woff += wsum[k];
        int carry = carry_s;
        if (i < n) a[i] = carry + woff + x - v;
        int tot = 0;
        for (int k = 0; k < 16; ++k) tot += wsum[k];
        __syncthreads();
        if (tid == 0) carry_s = carry + tot;
        __syncthreads();
    }
    if (tid == 0) a[n] = carry_s;
}

__global__ void k_scan_both(int* __restrict__ a, int na, int* __restrict__ b, int nb) {
    if (blockIdx.x == 0) scan_body(a, na);
    else scan_body(b, nb);
}

__global__ void k_scatter2way(const int* __restrict__ pv, const int* __restrict__ pe,
                              const int* __restrict__ bstart_v, const int* __restrict__ bstart_e,
                              int* __restrict__ cur_v, int* __restrict__ cur_e,
                              uint2* __restrict__ sorted_v, uint2* __restrict__ sorted_e, int P) {
    __shared__ int cv[256], ce[256], posv[256], pose[256];
    int tid = threadIdx.x;
    cv[tid] = 0; ce[tid] = 0;
    __syncthreads();
    int p0 = blockIdx.x * CHUNKA;
    int kv[CHUNKA / 256], ke[CHUNKA / 256];
    #pragma unroll
    for (int j = 0; j < CHUNKA / 256; ++j) {
        int p = p0 + tid + j * 256;
        if (p < P) {
            kv[j] = pv[p];
            ke[j] = pe[p];
            atomicAdd(&cv[kv[j] >> SH_V], 1);
            atomicAdd(&ce[ke[j] >> SH_E], 1);
        } else {
            kv[j] = -1;
            ke[j] = -1;
        }
    }
    __syncthreads();
    if (cv[tid]) posv[tid] = bstart_v[tid] + atomicAdd(&cur_v[tid], cv[tid]);
    if (ce[tid]) pose[tid] = bstart_e[tid] + atomicAdd(&cur_e[tid], ce[tid]);
    __syncthreads();
    #pragma unroll
    for (int j = 0; j < CHUNKA / 256; ++j) {
        if (kv[j] >= 0) {
            int iv = atomicAdd(&posv[kv[j] >> SH_V], 1);
            sorted_v[iv] = make_uint2((unsigned)kv[j], (unsigned)ke[j]);
            int ie = atomicAdd(&pose[ke[j] >> SH_E], 1);
            sorted_e[ie] = make_uint2((unsigned)ke[j], (unsigned)kv[j]);
        }
    }
}

template <int SUBD, int SH, int NSUB, int CSH>
__global__ __launch_bounds__(256) void k_build_ord(const uint2* __restrict__ sorted,
                                                   const int* __restrict__ bstart,
                                                   int* __restrict__ start_out,
                                                   int* __restrict__ deg_out,
                                                   int* __restrict__ csr_out, int D) {
    constexpr int NK2 = SUBD * NSUB;
    constexpr int STRIP = (NK2 + 255) / 256;
    __shared__ int cnt[NK2];
    __shared__ int wsum[4];
    int b = blockIdx.x;
    int tid = threadIdx.x;
    int base_key = b << SH;
    int s0 = bstart[b];
    int cntN = bstart[b + 1] - s0;
    for (int k = tid; k < NK2; k += 256) cnt[k] = 0;
    __syncthreads();
    for (int i = tid; i < cntN; i += 256) {
        uint2 pr = sorted[s0 + i];
        int k2 = ((int)pr.x - base_key) * NSUB + ((int)pr.y >> CSH);
        atomicAdd(&cnt[k2], 1);
    }
    __syncthreads();
    int local[STRIP];
    int sum = 0;
    int t0 = tid * STRIP;
    #pragma unroll
    for (int j = 0; j < STRIP; ++j) {
        int idx = t0 + j;
        local[j] = (idx < NK2) ? cnt[idx] : 0;
        sum += local[j];
    }
    int lane = tid & 63, w = tid >> 6;
    int x = sum;
    #pragma unroll
    for (int off = 1; off < 64; off <<= 1) {
        int t = __shfl_up(x, off);
        if (lane >= off) x += t;
    }
    if (lane == 63) wsum[w] = x;
    __syncthreads();
    int woff = 0;
    for (int k = 0; k < w; ++k) woff += wsum[k];
    int run = woff + x - sum;
    __syncthreads();
    #pragma unroll
    for (int j = 0; j < STRIP; ++j) {
        int idx = t0 + j;
        if (idx < NK2) {
            int tmp = local[j];
            cnt[idx] = run;
            run += tmp;
        }
    }
    __syncthreads();
    for (int loc = tid; loc < SUBD; loc += 256) {
        int key = base_key + loc;
        if (key < D) {
            int st = cnt[loc * NSUB];
            int en = (loc == SUBD - 1) ? cntN : cnt[(loc + 1) * NSUB];
            start_out[key] = s0 + st;
            deg_out[key] = en - st;
        }
    }
    __syncthreads();
    for (int i = tid; i < cntN; i += 256) {
        uint2 pr = sorted[s0 + i];
        int k2 = ((int)pr.x - base_key) * NSUB + ((int)pr.y >> CSH);
        int idx = atomicAdd(&cnt[k2], 1);
        csr_out[s0 + idx] = (int)pr.y;
    }
}

// ---------------- bucket-local degree sort: perm within each SUBD-sized bucket ----------------
// Preserves all spatial locality (csr/sv/start/deg/out stay in-bucket) while equalizing
// degrees across the 8 groups of each wave.
template <int SUBD>
__global__ void k_perm_local(const int* __restrict__ deg, int n, int* __restrict__ perm) {
    __shared__ int hist[256], pos[256];
    int b = blockIdx.x;
    int base = b * SUBD;
    int end = base + SUBD < n ? base + SUBD : n;
    int tid = threadIdx.x;
    hist[tid] = 0;
    __syncthreads();
    for (int i = base + tid; i < end; i += 256) {
        int d = deg[i];
        atomicAdd(&hist[d < 255 ? d : 255], 1);
    }
    __syncthreads();
    if (tid < 64) {
        int s0 = hist[tid * 4], s1 = hist[tid * 4 + 1], s2 = hist[tid * 4 + 2], s3 = hist[tid * 4 + 3];
        int sum = s0 + s1 + s2 + s3;
        int x = sum;
        #pragma unroll
        for (int off = 1; off < 64; off <<= 1) {
            int t = __shfl_up(x, off);
            if (tid >= off) x += t;
        }
        int excl = x - sum;
        pos[tid * 4] = excl;
        pos[tid * 4 + 1] = excl + s0;
        pos[tid * 4 + 2] = excl + s0 + s1;
        pos[tid * 4 + 3] = excl + s0 + s1 + s2;
    }
    __syncthreads();
    for (int i = base + tid; i < end; i += 256) {
        int d = deg[i];
        int r = atomicAdd(&pos[d < 255 ? d : 255], 1);
        perm[base + r] = i;
    }
}

// ---------------- fused weight prep ----------------
__global__ void k_prep(const float* __restrict__ W1, const float* __restrict__ b1,
                       const float* __restrict__ av1, const float* __restrict__ W2,
                       float* __restrict__ wav, float* __restrict__ bav,
                       u16* __restrict__ WcatT, u16* __restrict__ W2T) {
    int bid = blockIdx.x;
    int tid = threadIdx.x;
    if (bid < 4) {
        int h = bid;
        if (tid < DIN) {
            float s = 0.f;
            for (int j = 0; j < DH; ++j)
                s += W1[(size_t)(h * DIN + tid) * DH + j] * av1[h * DH + j];
            wav[h * DIN + tid] = s;
        }
        if (tid == 0) {
            float t = 0.f;
            for (int j = 0; j < DH; ++j) t += b1[h * DH + j] * av1[h * DH + j];
            bav[h] = t;
        }
    } else if (bid < 4 + 128) {
        int idx = (bid - 4) * 256 + tid;
        int c = idx >> 7, k = idx & 127;
        int h = c >> 6, j = c & 63;
        WcatT[c * DIN + k] = f2bf(W1[((size_t)h * DIN + k) * DH + j]);
    } else {
        int idx = (bid - 132) * 256 + tid;
        int c = idx >> 9, k = idx & 511;
        float v = (c < NC) ? W2[(size_t)k * NC + c] : 0.f;
        W2T[c * DCAT + k] = f2bf(v);
    }
}

// ---------------- conversion + node attention term ----------------
__global__ void k_conv(const float* __restrict__ X0, const float* __restrict__ X1,
                       const float* __restrict__ wav, const float* __restrict__ bav,
                       u16* __restrict__ Xbi, float* __restrict__ sv8, int N) {
    int wave = (blockIdx.x * blockDim.x + threadIdx.x) >> 6;
    int lane = threadIdx.x & 63;
    if (wave >= N) return;
    int xz = blockIdx.y;
    const float* X = xz ? X1 : X0;
    float2 a = *(const float2*)(X + (size_t)wave * DIN + lane * 2);
    unsigned int packed = (unsigned int)f2bf(a.x) | ((unsigned int)f2bf(a.y) << 16);
    *(unsigned int*)(Xbi + (size_t)wave * 256 + xz * 128 + lane * 2) = packed;
    float s[NH];
    #pragma unroll
    for (int h = 0; h < NH; ++h) {
        float2 wv = *(const float2*)(wav + h * DIN + lane * 2);
        float t = a.x * wv.x + a.y * wv.y;
        #pragma unroll
        for (int off = 32; off >= 1; off >>= 1) t += __shfl_xor(t, off);
        s[h] = t;
    }
    if (lane == 0) {
        #pragma unroll
        for (int h = 0; h < NH; ++h) sv8[(size_t)(xz * 4 + h) * N + wave] = s[h] + bav[h];
    }
}

// ---------------- edge mean (layer 1) ----------------
__global__ void k_edge_mean1(const u16* __restrict__ Xbi, const int* __restrict__ start_e,
                             const int* __restrict__ deg_e, const int* __restrict__ csr_e_v,
                             u16* __restrict__ Xbar0, u16* __restrict__ Xbar1, int E) {
    int wave = (blockIdx.x * blockDim.x + threadIdx.x) >> 6;
    int lane = threadIdx.x & 63;
    if (wave >= E) return;
    int s = start_e[wave], t = s + deg_e[wave];
    int q = lane >> 4, c = lane & 15;
    float a0[8], a1[8];
    #pragma unroll
    for (int j = 0; j < 8; ++j) { a0[j] = 0.f; a1[j] = 0.f; }
    int i = s + q;
    u16x8 y0A = {0}, y1A = {0}, y0B = {0}, y1B = {0}, y0C = {0}, y1C = {0};
#define EM1_LOAD(Y0, Y1, IDX) { int v_ = csr_e_v[IDX]; \
        const u16* yp_ = Xbi + (size_t)v_ * 256 + c * 8; \
        Y0 = *(const u16x8*)yp_; Y1 = *(const u16x8*)(yp_ + 128); }
#define EM1_CONSUME(Y0, Y1) { \
        _Pragma("unroll") \
        for (int j = 0; j < 8; ++j) { a0[j] += bf2f(Y0[j]); a1[j] += bf2f(Y1[j]); } }
    if (i < t) EM1_LOAD(y0A, y1A, i);
    if (i + 4 < t) EM1_LOAD(y0B, y1B, i + 4);
    if (i + 8 < t) EM1_LOAD(y0C, y1C, i + 8);
    for (; i + 8 < t; i += 12) {
        EM1_CONSUME(y0A, y1A);
        if (i + 12 < t) EM1_LOAD(y0A, y1A, i + 12);
        EM1_CONSUME(y0B, y1B);
        if (i + 16 < t) EM1_LOAD(y0B, y1B, i + 16);
        EM1_CONSUME(y0C, y1C);
        if (i + 20 < t) EM1_LOAD(y0C, y1C, i + 20);
    }
    if (i < t) EM1_CONSUME(y0A, y1A);
    if (i + 4 < t) EM1_CONSUME(y0B, y1B);
#undef EM1_LOAD
#undef EM1_CONSUME
    #pragma unroll
    for (int j = 0; j < 8; ++j) {
        a0[j] += __shfl_xor(a0[j], 16);
        a0[j] += __shfl_xor(a0[j], 32);
        a1[j] += __shfl_xor(a1[j], 16);
        a1[j] += __shfl_xor(a1[j], 32);
    }
    int deg = t - s;
    float inv = 1.f / (float)(deg > 1 ? deg : 1);
    if (q == 0) {
        u16x8 r0, r1;
        #pragma unroll
        for (int j = 0; j < 8; ++j) { r0[j] = f2bf(a0[j] * inv); r1[j] = f2bf(a1[j] * inv); }
        *(u16x8*)(Xbar0 + (size_t)wave * DIN + c * 8) = r0;
        *(u16x8*)(Xbar1 + (size_t)wave * DIN + c * 8) = r1;
    }
}

// ---------------- MFMA GEMM with fused row-dot epilogue ----------------
template <int KDIM, int NTILES, int DOTMODE>
__global__ __launch_bounds__(256) void k_gemm_mfma(const u16* __restrict__ A0,
                                                   const u16* __restrict__ A1, int M,
                                                   const u16* __restrict__ Bt,
                                                   const float* __restrict__ bias,
                                                   u16* __restrict__ out0, u16* __restrict__ out1,
                                                   int ldo, int ncols,
                                                   const float* __restrict__ dvec,
                                                   float* __restrict__ dout) {
    constexpr int LDB = KDIM + 8;
    __shared__ u16 Bs[NTILES * 16 * LDB];
    const u16* A = blockIdx.z ? A1 : A0;
    u16* out = blockIdx.z ? out1 : out0;
    int tid = threadIdx.x;
    int colbase = blockIdx.y * NTILES * 16;
    const u16* Btblk = Bt + (size_t)colbase * KDIM;
    for (int idx = tid * 4; idx < NTILES * 16 * KDIM; idx += 256 * 4) {
        int c = idx / KDIM, k = idx % KDIM;
        *(u16x4*)&Bs[c * LDB + k] = *(const u16x4*)(Btblk + c * KDIM + k);
    }
    __syncthreads();
    int w = tid >> 6, lane = tid & 63;
    int r0 = blockIdx.x * 64 + w * 16;
    int arow = r0 + (lane & 15);
    bool avalid = arow < M;
    const u16* ap = A + (size_t)arow * KDIM + (lane >> 4) * 8;
    f32x4 acc[NTILES];
    #pragma unroll
    for (int nt = 0; nt < NTILES; ++nt) acc[nt] = (f32x4){0.f, 0.f, 0.f, 0.f};
    #pragma unroll
    for (int k0 = 0; k0 < KDIM; k0 += 32) {
        bf16x8 a = (bf16x8)(short)0;
        if (avalid) a = *(const bf16x8*)(ap + k0);
        #pragma unroll
        for (int nt = 0; nt < NTILES; ++nt) {
            bf16x8 b = *(const bf16x8*)&Bs[(nt * 16 + (lane & 15)) * LDB + k0 + (lane >> 4) * 8];
            acc[nt] = __builtin_amdgcn_mfma_f32_16x16x32_bf16(a, b, acc[nt], 0, 0, 0);
        }
    }
    #pragma unroll
    for (int j = 0; j < 4; ++j) {
        int row = r0 + (lane >> 4) * 4 + j;
        float pA = 0.f, pB = 0.f;
        #pragma unroll
        for (int nt = 0; nt < NTILES; ++nt) {
            int col = colbase + nt * 16 + (lane & 15);
            bool cok = col < ncols;
            float val = cok ? acc[nt][j] + bias[col] : 0.f;
            if (DOTMODE == 1) {
                float dv = dvec[col];
                if (nt < NTILES / 2) pA += val * dv; else pB += val * dv;
            } else if (DOTMODE == 2) {
                pA += cok ? val * dvec[col] : 0.f;
            }
            if (row < M && cok) out[(size_t)row * ldo + col] = f2bf(val);
        }
        if (DOTMODE) {
            pA += __shfl_xor(pA, 1);
            pA += __shfl_xor(pA, 2);
            pA += __shfl_xor(pA, 4);
            pA += __shfl_xor(pA, 8);
            if (DOTMODE == 1) {
                pB += __shfl_xor(pB, 1);
                pB += __shfl_xor(pB, 2);
                pB += __shfl_xor(pB, 4);
                pB += __shfl_xor(pB, 8);
            }
            if ((lane & 15) == 0 && row < M) {
                if (DOTMODE == 1) {
                    int hbase = blockIdx.y * 2;
                    int z = blockIdx.z;
                    dout[(size_t)(z * 4 + hbase) * M + row] = pA;
                    dout[(size_t)(z * 4 + hbase + 1) * M + row] = pB;
                } else {
                    dout[row] = pA;
                }
            }
        }
    }
}

// ---------------- node pass (layer 1): XCD-sliced, group-per-node (bucket-local deg-sorted) ----------------
__global__ void k_node_pass1(const u16* __restrict__ Ycat, const float* __restrict__ se8,
                             const float* __restrict__ sv8, const int* __restrict__ start_v,
                             const int* __restrict__ deg_v, const int* __restrict__ csr_v_e,
                             const int* __restrict__ perm, u16* __restrict__ hbuf,
                             int N, int E) {
    int bid = blockIdx.x;
    int s = bid & 7;
    int warp = threadIdx.x >> 6;
    int lane = threadIdx.x & 63;
    int g = lane >> 3, c = lane & 7;
    int gidx = (bid >> 3) * 32 + warp * 8 + g;
    if (gidx >= N) return;
    int node = perm[gidx];   // bucket-local deg sort: equal-degree groups, locality preserved
    int p0 = start_v[node];
    int p1 = p0 + deg_v[node];
    float sv = sv8[(size_t)s * N + node];
    const float* seS = se8 + (size_t)s * E;
    const u16* ybase = Ycat + s * 64 + c * 8;
    float den = 0.f;
    float acc[8];
    #pragma unroll
    for (int j = 0; j < 8; ++j) acc[j] = 0.f;
    float sA = 0.f, sB = 0.f;
    u16x8 yA = {0}, yB = {0};
#define NP1_LOAD(S, Y, IDX) { int e_ = csr_v_e[IDX]; S = seS[e_]; \
        Y = *(const u16x8*)(ybase + (size_t)e_ * 512); }
#define NP1_CONSUME(S, Y) { \
        float x_ = S + sv; x_ = fmaxf(x_, 0.2f * x_); float ex_ = __expf(x_); \
        den += ex_; \
        _Pragma("unroll") \
        for (int j = 0; j < 8; ++j) acc[j] += ex_ * bf2f(Y[j]); }
    int i = p0;
    if (i < p1) NP1_LOAD(sA, yA, i);
    if (i + 1 < p1) NP1_LOAD(sB, yB, i + 1);
    for (; i + 1 < p1; i += 2) {
        NP1_CONSUME(sA, yA);
        if (i + 2 < p1) NP1_LOAD(sA, yA, i + 2);
        NP1_CONSUME(sB, yB);
        if (i + 3 < p1) NP1_LOAD(sB, yB, i + 3);
    }
    if (i < p1) NP1_CONSUME(sA, yA);
#undef NP1_LOAD
#undef NP1_CONSUME
    float inv = (p1 > p0) ? 1.f / den : 0.f;
    u16x8 r;
    #pragma unroll
    for (int j = 0; j < 8; ++j) {
        float o = acc[j] * inv;
        o = o > 0.f ? o : __expf(o) - 1.f;
        r[j] = f2bf(o);
    }
    *(u16x8*)(hbuf + (size_t)node * DCAT + s * 64 + c * 8) = r;
}

// ---------------- layer 2: group-per-segment, bucket-local deg-sorted ----------------

__global__ void k_edge_mean2(const u16* __restrict__ Xp2b, const int* __restrict__ start_e,
                             const int* __restrict__ deg_ea, const int* __restrict__ csr_e_v,
                             const int* __restrict__ perm, u16* __restrict__ Y2b,
                             const float* __restrict__ ae2, float* __restrict__ se2, int E) {
    int warp = threadIdx.x >> 6;
    int lane = threadIdx.x & 63;
    int g = lane >> 3, c = lane & 7;
    int gidx = blockIdx.x * 32 + warp * 8 + g;
    if (gidx >= E) return;
    int edge = perm[gidx];
    int p0 = start_e[edge], p1 = p0 + deg_ea[edge];
    bool act = c < 5;
    const u16* xbase = Xp2b + c * 8;
    float acc[8];
    #pragma unroll
    for (int j = 0; j < 8; ++j) acc[j] = 0.f;
    if (act) {
        for (int i = p0; i < p1; ++i) {
            int v = csr_e_v[i];
            u16x8 y = *(const u16x8*)(xbase + (size_t)v * NC);
            #pragma unroll
            for (int j = 0; j < 8; ++j) acc[j] += bf2f(y[j]);
        }
    }
    int deg = p1 - p0;
    float inv = 1.f / (float)(deg > 1 ? deg : 1);
    float p = 0.f;
    if (act) {
        u16x8 r;
        #pragma unroll
        for (int j = 0; j < 8; ++j) {
            float y = acc[j] * inv;
            p += y * ae2[c * 8 + j];
            r[j] = f2bf(y);
        }
        *(u16x8*)(Y2b + (size_t)edge * NC + c * 8) = r;
    }
    p += __shfl_xor(p, 1);
    p += __shfl_xor(p, 2);
    p += __shfl_xor(p, 4);
    if (c == 0) se2[edge] = p;
}

__global__ void k_node_pass2(const u16* __restrict__ Y2b, const float* __restrict__ se2,
                             const float* __restrict__ sv2, const int* __restrict__ start_v,
                             const int* __restrict__ deg_va, const int* __restrict__ csr_v_e,
                             const int* __restrict__ perm, float* __restrict__ out, int N) {
    int warp = threadIdx.x >> 6;
    int lane = threadIdx.x & 63;
    int g = lane >> 3, c = lane & 7;
    int gidx = blockIdx.x * 32 + warp * 8 + g;
    if (gidx >= N) return;
    int node = perm[gidx];
    int p0 = start_v[node], p1 = p0 + deg_va[node];
    bool act = c < 5;
    float* orow = out + (size_t)node * NC;
    if (p1 == p0) {
        if (act) {
            *(float4*)(orow + c * 8) = make_float4(0.f, 0.f, 0.f, 0.f);
            *(float4*)(orow + c * 8 + 4) = make_float4(0.f, 0.f, 0.f, 0.f);
        }
        return;
    }
    float svv = sv2[node];
    const u16* ybase = Y2b + c * 8;
    float den = 0.f;
    float acc[8];
    #pragma unroll
    for (int j = 0; j < 8; ++j) acc[j] = 0.f;
    for (int i = p0; i < p1; ++i) {
        int e = csr_v_e[i];
        float x = se2[e] + svv;
        x = fmaxf(x, 0.2f * x);
        float ex = __expf(x);
        den += ex;
        if (act) {
            u16x8 y = *(const u16x8*)(ybase + (size_t)e * NC);
            #pragma unroll
            for (int j = 0; j < 8; ++j) acc[j] += ex * bf2f(y[j]);
        }
    }
    if (act) {
        float inv = 1.f / den;
        float o[8];
        #pragma unroll
        for (int j = 0; j < 8; ++j) {
            float v = acc[j] * inv;
            o[j] = v > 0.f ? v : __expf(v) - 1.f;
        }
        *(float4*)(orow + c * 8) = make_float4(o[0], o[1], o[2], o[3]);
        *(float4*)(orow + c * 8 + 4) = make_float4(o[4], o[5], o[6], o[7]);
    }
}

// ---------------- launcher ----------------
extern "C" void kernel_launch(void* const* d_in, const int* in_sizes, int n_in,
                              void* d_out, int out_size, void* d_ws, size_t ws_size,
                              hipStream_t stream) {
    const float* x0 = (const float*)d_in[0];
    const float* x1 = (const float*)d_in[1];
    const float* W1 = (const float*)d_in[2];
    const float* b1 = (const float*)d_in[3];
    const float* ae1 = (const float*)d_in[4];
    const float* av1 = (const float*)d_in[5];
    const float* W2 = (const float*)d_in[6];
    const float* b2 = (const float*)d_in[7];
    const float* ae2 = (const float*)d_in[8];
    const float* av2 = (const float*)d_in[9];
    const int* pe = (const int*)d_in[10];
    const int* pv = (const int*)d_in[11];

    const int N = in_sizes[0] / DIN;  // 100000
    const int P = in_sizes[10];       // 1600000
    const int E = E_CONST;            // 20000
    const int NBKT_V = (N + SUBD_V - 1) / SUBD_V;   // 196
    const int NBKT_E = (E + SUBD_E - 1) / SUBD_E;   // 157

    char* base = (char*)d_ws;
    auto alloc = [&](size_t bytes) -> void* {
        void* p = (void*)base;
        base += (bytes + 255) & ~(size_t)255;
        return p;
    };
    u16* Xbi = (u16*)alloc((size_t)N * 256 * 2);
    u16* hbuf = (u16*)alloc((size_t)N * DCAT * 2);
    u16* Xbar0 = (u16*)alloc((size_t)E * DIN * 2);
    u16* Xbar1 = (u16*)alloc((size_t)E * DIN * 2);
    u16* Ycat = (u16*)alloc((size_t)E * 512 * 2);
    u16* Xp2b = (u16*)alloc((size_t)N * NC * 2);
    u16* Y2b = (u16*)alloc((size_t)E * NC * 2);
    float* se8 = (float*)alloc((size_t)8 * E * 4);
    float* se2 = (float*)alloc((size_t)E * 4);
    float* sv8 = (float*)alloc((size_t)8 * N * 4);
    float* sv2 = (float*)alloc((size_t)N * 4);
    float* wav = (float*)alloc((size_t)NH * DIN * 4);
    float* bav = (float*)alloc((size_t)NH * 4);
    u16* WcatT = (u16*)alloc((size_t)256 * DIN * 2);
    u16* W2T = (u16*)alloc((size_t)48 * DCAT * 2);
    uint2* sorted_v = (uint2*)alloc((size_t)P * 8);
    uint2* sorted_e = (uint2*)alloc((size_t)P * 8);
    int* start_v = (int*)alloc((size_t)N * 4);
    int* deg_v = (int*)alloc((size_t)N * 4);
    int* start_e = (int*)alloc((size_t)E * 4);
    int* deg_e = (int*)alloc((size_t)E * 4);
    int* csr_v_e = (int*)alloc((size_t)P * 4);
    int* csr_e_v = (int*)alloc((size_t)P * 4);
    int* perm_v = (int*)alloc((size_t)N * 4);
    int* perm_e = (int*)alloc((size_t)E * 4);
    char* zstart = base;
    int* bstart_v = (int*)alloc((size_t)(NBKT_V + 1) * 4);
    int* bstart_e = (int*)alloc((size_t)(NBKT_E + 1) * 4);
    int* cur_v = (int*)alloc((size_t)256 * 4);
    int* cur_e = (int*)alloc((size_t)256 * 4);
    size_t zbytes = (size_t)(base - zstart);

    if ((size_t)(base - (char*)d_ws) > ws_size) return;

    hipMemsetAsync(zstart, 0, zbytes, stream);

    dim3 b256(256);
    int nA = (P + CHUNKA - 1) / CHUNKA;   // 391
    k_hist2<<<nA, b256, 0, stream>>>(pv, pe, bstart_v, bstart_e, P);
    k_scan_both<<<2, 1024, 0, stream>>>(bstart_v, NBKT_V, bstart_e, NBKT_E);
    k_scatter2way<<<nA, b256, 0, stream>>>(pv, pe, bstart_v, bstart_e, cur_v, cur_e,
                                           sorted_v, sorted_e, P);
    k_build_ord<SUBD_V, SH_V, NSUB_E, ECH><<<NBKT_V, b256, 0, stream>>>(sorted_v, bstart_v,
                                                                        start_v, deg_v,
                                                                        csr_v_e, N);
    k_build_ord<SUBD_E, SH_E, NSUB_V, VCH><<<NBKT_E, b256, 0, stream>>>(sorted_e, bstart_e,
                                                                        start_e, deg_e,
                                                                        csr_e_v, E);

    // bucket-local degree sort -> perm_v, perm_e (locality-preserving)
    k_perm_local<SUBD_V><<<NBKT_V, b256, 0, stream>>>(deg_v, N, perm_v);
    k_perm_local<SUBD_E><<<NBKT_E, b256, 0, stream>>>(deg_e, E, perm_e);

    k_prep<<<228, b256, 0, stream>>>(W1, b1, av1, W2, wav, bav, WcatT, W2T);

    int gN4 = (N + 3) / 4;
    int gE4 = (E + 3) / 4;
    dim3 gconv(gN4, 2);
    k_conv<<<gconv, b256, 0, stream>>>(x0, x1, wav, bav, Xbi, sv8, N);

    k_edge_mean1<<<gE4, b256, 0, stream>>>(Xbi, start_e, deg_e, csr_e_v, Xbar0, Xbar1, E);
    dim3 g1((E + 63) / 64, 2, 2);
    k_gemm_mfma<DIN, 8, 1><<<g1, b256, 0, stream>>>(Xbar0, Xbar1, E, WcatT, b1,
                                                    Ycat, Ycat + 256, 512, 256, ae1, se8);
    int gnp1 = ((N + 31) / 32) * 8;
    k_node_pass1<<<gnp1, b256, 0, stream>>>(Ycat, se8, sv8, start_v, deg_v, csr_v_e,
                                            perm_v, hbuf, N, E);

    dim3 g2((N + 63) / 64, 1, 1);
    k_gemm_mfma<DCAT, 3, 2><<<g2, b256, 0, stream>>>(hbuf, hbuf, N, W2T, b2, Xp2b, Xp2b,
                                                     NC, NC, av2, sv2);
    int gseg = (E + 31) / 32;
    k_edge_mean2<<<gseg, b256, 0, stream>>>(Xp2b, start_e, deg_e, csr_e_v, perm_e,
                                            Y2b, ae2, se2, E);
    int gnp2 = (N + 31) / 32;
    k_node_pass2<<<gnp2, b256, 0, stream>>>(Y2b, se2, sv2, start_v, deg_v, csr_v_e,
                                            perm_v, (float*)d_out, N);
}

// Round 15
// 602.739 us; speedup vs baseline: 1.1232x; 1.0318x over previous
//
#include <hip/hip_runtime.h>
#include <cstdint>
#include <cstddef>

// N=100000, E=20000, P=1600000, din=128, dh=64, H=4, DCAT=512, C=40
static constexpr int DIN = 128;
static constexpr int DH = 64;
static constexpr int NH = 4;
static constexpr int DCAT = 512;
static constexpr int NC = 40;
static constexpr int E_CONST = 20000;
static constexpr int SH_V = 9, SUBD_V = 512;
static constexpr int SH_E = 7, SUBD_E = 128;
static constexpr int ECH = 11, NSUB_E = 10;
static constexpr int VCH = 12, NSUB_V = 25;
static constexpr int CHUNKA = 4096;

typedef unsigned short u16;
typedef __attribute__((ext_vector_type(4))) unsigned short u16x4;
typedef __attribute__((ext_vector_type(8))) unsigned short u16x8;
typedef __attribute__((ext_vector_type(8))) short bf16x8;
typedef __attribute__((ext_vector_type(4))) float f32x4;

static __device__ __forceinline__ float bf2f(u16 u) {
    union { unsigned int i; float f; } x;
    x.i = ((unsigned int)u) << 16;
    return x.f;
}
static __device__ __forceinline__ u16 f2bf(float f) {
    union { float f; unsigned int i; } x;
    x.f = f;
    unsigned int r = x.i + 0x7fffu + ((x.i >> 16) & 1u);
    return (u16)(r >> 16);
}

// ---------------- CSR build ----------------

__global__ void k_hist2(const int* __restrict__ pv, const int* __restrict__ pe,
                        int* __restrict__ btot_v, int* __restrict__ btot_e, int P) {
    __shared__ int cv[256], ce[256];
    int tid = threadIdx.x;
    cv[tid] = 0; ce[tid] = 0;
    __syncthreads();
    int p0 = blockIdx.x * CHUNKA;
    #pragma unroll
    for (int j = 0; j < CHUNKA / 256; ++j) {
        int p = p0 + tid + j * 256;
        if (p < P) {
            atomicAdd(&cv[pv[p] >> SH_V], 1);
            atomicAdd(&ce[pe[p] >> SH_E], 1);
        }
    }
    __syncthreads();
    if (cv[tid]) atomicAdd(&btot_v[tid], cv[tid]);
    if (ce[tid]) atomicAdd(&btot_e[tid], ce[tid]);
}

static __device__ void scan_body(int* a, int n) {
    __shared__ int wsum[16];
    __shared__ int carry_s;
    int tid = threadIdx.x;
    int lane = tid & 63;
    int w = tid >> 6;
    if (tid == 0) carry_s = 0;
    __syncthreads();
    for (int base = 0; base < n; base += 1024) {
        int i = base + tid;
        int v = (i < n) ? a[i] : 0;
        int x = v;
        #pragma unroll
        for (int off = 1; off < 64; off <<= 1) {
            int t = __shfl_up(x, off);
            if (lane >= off) x += t;
        }
        if (lane == 63) wsum[w] = x;
        __syncthreads();
        int woff = 0;
        for (int k = 0; k < w; ++k) woff += wsum[k];
        int carry = carry_s;
        if (i < n) a[i] = carry + woff + x - v;
        int tot = 0;
        for (int k = 0; k < 16; ++k) tot += wsum[k];
        __syncthreads();
        if (tid == 0) carry_s = carry + tot;
        __syncthreads();
    }
    if (tid == 0) a[n] = carry_s;
}

__global__ void k_scan_both(int* __restrict__ a, int na, int* __restrict__ b, int nb) {
    if (blockIdx.x == 0) scan_body(a, na);
    else scan_body(b, nb);
}

__global__ void k_scatter2way(const int* __restrict__ pv, const int* __restrict__ pe,
                              const int* __restrict__ bstart_v, const int* __restrict__ bstart_e,
                              int* __restrict__ cur_v, int* __restrict__ cur_e,
                              uint2* __restrict__ sorted_v, uint2* __restrict__ sorted_e, int P) {
    __shared__ int cv[256], ce[256], posv[256], pose[256];
    int tid = threadIdx.x;
    cv[tid] = 0; ce[tid] = 0;
    __syncthreads();
    int p0 = blockIdx.x * CHUNKA;
    int kv[CHUNKA / 256], ke[CHUNKA / 256];
    #pragma unroll
    for (int j = 0; j < CHUNKA / 256; ++j) {
        int p = p0 + tid + j * 256;
        if (p < P) {
            kv[j] = pv[p];
            ke[j] = pe[p];
            atomicAdd(&cv[kv[j] >> SH_V], 1);
            atomicAdd(&ce[ke[j] >> SH_E], 1);
        } else {
            kv[j] = -1;
            ke[j] = -1;
        }
    }
    __syncthreads();
    if (cv[tid]) posv[tid] = bstart_v[tid] + atomicAdd(&cur_v[tid], cv[tid]);
    if (ce[tid]) pose[tid] = bstart_e[tid] + atomicAdd(&cur_e[tid], ce[tid]);
    __syncthreads();
    #pragma unroll
    for (int j = 0; j < CHUNKA / 256; ++j) {
        if (kv[j] >= 0) {
            int iv = atomicAdd(&posv[kv[j] >> SH_V], 1);
            sorted_v[iv] = make_uint2((unsigned)kv[j], (unsigned)ke[j]);
            int ie = atomicAdd(&pose[ke[j] >> SH_E], 1);
            sorted_e[ie] = make_uint2((unsigned)ke[j], (unsigned)kv[j]);
        }
    }
}

template <int SUBD, int SH, int NSUB, int CSH>
__global__ __launch_bounds__(256) void k_build_ord(const uint2* __restrict__ sorted,
                                                   const int* __restrict__ bstart,
                                                   int* __restrict__ start_out,
                                                   int* __restrict__ deg_out,
                                                   int* __restrict__ csr_out, int D) {
    constexpr int NK2 = SUBD * NSUB;
    constexpr int STRIP = (NK2 + 255) / 256;
    __shared__ int cnt[NK2];
    __shared__ int wsum[4];
    int b = blockIdx.x;
    int tid = threadIdx.x;
    int base_key = b << SH;
    int s0 = bstart[b];
    int cntN = bstart[b + 1] - s0;
    for (int k = tid; k < NK2; k += 256) cnt[k] = 0;
    __syncthreads();
    for (int i = tid; i < cntN; i += 256) {
        uint2 pr = sorted[s0 + i];
        int k2 = ((int)pr.x - base_key) * NSUB + ((int)pr.y >> CSH);
        atomicAdd(&cnt[k2], 1);
    }
    __syncthreads();
    int local[STRIP];
    int sum = 0;
    int t0 = tid * STRIP;
    #pragma unroll
    for (int j = 0; j < STRIP; ++j) {
        int idx = t0 + j;
        local[j] = (idx < NK2) ? cnt[idx] : 0;
        sum += local[j];
    }
    int lane = tid & 63, w = tid >> 6;
    int x = sum;
    #pragma unroll
    for (int off = 1; off < 64; off <<= 1) {
        int t = __shfl_up(x, off);
        if (lane >= off) x += t;
    }
    if (lane == 63) wsum[w] = x;
    __syncthreads();
    int woff = 0;
    for (int k = 0; k < w; ++k) woff += wsum[k];
    int run = woff + x - sum;
    __syncthreads();
    #pragma unroll
    for (int j = 0; j < STRIP; ++j) {
        int idx = t0 + j;
        if (idx < NK2) {
            int tmp = local[j];
            cnt[idx] = run;
            run += tmp;
        }
    }
    __syncthreads();
    for (int loc = tid; loc < SUBD; loc += 256) {
        int key = base_key + loc;
        if (key < D) {
            int st = cnt[loc * NSUB];
            int en = (loc == SUBD - 1) ? cntN : cnt[(loc + 1) * NSUB];
            start_out[key] = s0 + st;
            deg_out[key] = en - st;
        }
    }
    __syncthreads();
    for (int i = tid; i < cntN; i += 256) {
        uint2 pr = sorted[s0 + i];
        int k2 = ((int)pr.x - base_key) * NSUB + ((int)pr.y >> CSH);
        int idx = atomicAdd(&cnt[k2], 1);
        csr_out[s0 + idx] = (int)pr.y;
    }
}

// ---------------- fused weight prep ----------------
__global__ void k_prep(const float* __restrict__ W1, const float* __restrict__ b1,
                       const float* __restrict__ av1, const float* __restrict__ W2,
                       float* __restrict__ wav, float* __restrict__ bav,
                       u16* __restrict__ WcatT, u16* __restrict__ W2T) {
    int bid = blockIdx.x;
    int tid = threadIdx.x;
    if (bid < 4) {
        int h = bid;
        if (tid < DIN) {
            float s = 0.f;
            for (int j = 0; j < DH; ++j)
                s += W1[(size_t)(h * DIN + tid) * DH + j] * av1[h * DH + j];
            wav[h * DIN + tid] = s;
        }
        if (tid == 0) {
            float t = 0.f;
            for (int j = 0; j < DH; ++j) t += b1[h * DH + j] * av1[h * DH + j];
            bav[h] = t;
        }
    } else if (bid < 4 + 128) {
        int idx = (bid - 4) * 256 + tid;
        int c = idx >> 7, k = idx & 127;
        int h = c >> 6, j = c & 63;
        WcatT[c * DIN + k] = f2bf(W1[((size_t)h * DIN + k) * DH + j]);
    } else {
        int idx = (bid - 132) * 256 + tid;
        int c = idx >> 9, k = idx & 511;
        float v = (c < NC) ? W2[(size_t)k * NC + c] : 0.f;
        W2T[c * DCAT + k] = f2bf(v);
    }
}

// ---------------- conversion + node attention term ----------------
__global__ void k_conv(const float* __restrict__ X0, const float* __restrict__ X1,
                       const float* __restrict__ wav, const float* __restrict__ bav,
                       u16* __restrict__ Xbi, float* __restrict__ sv8, int N) {
    int wave = (blockIdx.x * blockDim.x + threadIdx.x) >> 6;
    int lane = threadIdx.x & 63;
    if (wave >= N) return;
    int xz = blockIdx.y;
    const float* X = xz ? X1 : X0;
    float2 a = *(const float2*)(X + (size_t)wave * DIN + lane * 2);
    unsigned int packed = (unsigned int)f2bf(a.x) | ((unsigned int)f2bf(a.y) << 16);
    *(unsigned int*)(Xbi + (size_t)wave * 256 + xz * 128 + lane * 2) = packed;
    float s[NH];
    #pragma unroll
    for (int h = 0; h < NH; ++h) {
        float2 wv = *(const float2*)(wav + h * DIN + lane * 2);
        float t = a.x * wv.x + a.y * wv.y;
        #pragma unroll
        for (int off = 32; off >= 1; off >>= 1) t += __shfl_xor(t, off);
        s[h] = t;
    }
    if (lane == 0) {
        #pragma unroll
        for (int h = 0; h < NH; ++h) sv8[(size_t)(xz * 4 + h) * N + wave] = s[h] + bav[h];
    }
}

// ---------------- edge mean (layer 1) ----------------
__global__ void k_edge_mean1(const u16* __restrict__ Xbi, const int* __restrict__ start_e,
                             const int* __restrict__ deg_e, const int* __restrict__ csr_e_v,
                             u16* __restrict__ Xbar0, u16* __restrict__ Xbar1, int E) {
    int wave = (blockIdx.x * blockDim.x + threadIdx.x) >> 6;
    int lane = threadIdx.x & 63;
    if (wave >= E) return;
    int s = start_e[wave], t = s + deg_e[wave];
    int q = lane >> 4, c = lane & 15;
    float a0[8], a1[8];
    #pragma unroll
    for (int j = 0; j < 8; ++j) { a0[j] = 0.f; a1[j] = 0.f; }
    int i = s + q;
    u16x8 y0A = {0}, y1A = {0}, y0B = {0}, y1B = {0}, y0C = {0}, y1C = {0};
#define EM1_LOAD(Y0, Y1, IDX) { int v_ = csr_e_v[IDX]; \
        const u16* yp_ = Xbi + (size_t)v_ * 256 + c * 8; \
        Y0 = *(const u16x8*)yp_; Y1 = *(const u16x8*)(yp_ + 128); }
#define EM1_CONSUME(Y0, Y1) { \
        _Pragma("unroll") \
        for (int j = 0; j < 8; ++j) { a0[j] += bf2f(Y0[j]); a1[j] += bf2f(Y1[j]); } }
    if (i < t) EM1_LOAD(y0A, y1A, i);
    if (i + 4 < t) EM1_LOAD(y0B, y1B, i + 4);
    if (i + 8 < t) EM1_LOAD(y0C, y1C, i + 8);
    for (; i + 8 < t; i += 12) {
        EM1_CONSUME(y0A, y1A);
        if (i + 12 < t) EM1_LOAD(y0A, y1A, i + 12);
        EM1_CONSUME(y0B, y1B);
        if (i + 16 < t) EM1_LOAD(y0B, y1B, i + 16);
        EM1_CONSUME(y0C, y1C);
        if (i + 20 < t) EM1_LOAD(y0C, y1C, i + 20);
    }
    if (i < t) EM1_CONSUME(y0A, y1A);
    if (i + 4 < t) EM1_CONSUME(y0B, y1B);
#undef EM1_LOAD
#undef EM1_CONSUME
    #pragma unroll
    for (int j = 0; j < 8; ++j) {
        a0[j] += __shfl_xor(a0[j], 16);
        a0[j] += __shfl_xor(a0[j], 32);
        a1[j] += __shfl_xor(a1[j], 16);
        a1[j] += __shfl_xor(a1[j], 32);
    }
    int deg = t - s;
    float inv = 1.f / (float)(deg > 1 ? deg : 1);
    if (q == 0) {
        u16x8 r0, r1;
        #pragma unroll
        for (int j = 0; j < 8; ++j) { r0[j] = f2bf(a0[j] * inv); r1[j] = f2bf(a1[j] * inv); }
        *(u16x8*)(Xbar0 + (size_t)wave * DIN + c * 8) = r0;
        *(u16x8*)(Xbar1 + (size_t)wave * DIN + c * 8) = r1;
    }
}

// ---------------- MFMA GEMM with fused row-dot epilogue ----------------
template <int KDIM, int NTILES, int DOTMODE>
__global__ __launch_bounds__(256) void k_gemm_mfma(const u16* __restrict__ A0,
                                                   const u16* __restrict__ A1, int M,
                                                   const u16* __restrict__ Bt,
                                                   const float* __restrict__ bias,
                                                   u16* __restrict__ out0, u16* __restrict__ out1,
                                                   int ldo, int ncols,
                                                   const float* __restrict__ dvec,
                                                   float* __restrict__ dout) {
    constexpr int LDB = KDIM + 8;
    __shared__ u16 Bs[NTILES * 16 * LDB];
    const u16* A = blockIdx.z ? A1 : A0;
    u16* out = blockIdx.z ? out1 : out0;
    int tid = threadIdx.x;
    int colbase = blockIdx.y * NTILES * 16;
    const u16* Btblk = Bt + (size_t)colbase * KDIM;
    for (int idx = tid * 4; idx < NTILES * 16 * KDIM; idx += 256 * 4) {
        int c = idx / KDIM, k = idx % KDIM;
        *(u16x4*)&Bs[c * LDB + k] = *(const u16x4*)(Btblk + c * KDIM + k);
    }
    __syncthreads();
    int w = tid >> 6, lane = tid & 63;
    int r0 = blockIdx.x * 64 + w * 16;
    int arow = r0 + (lane & 15);
    bool avalid = arow < M;
    const u16* ap = A + (size_t)arow * KDIM + (lane >> 4) * 8;
    f32x4 acc[NTILES];
    #pragma unroll
    for (int nt = 0; nt < NTILES; ++nt) acc[nt] = (f32x4){0.f, 0.f, 0.f, 0.f};
    #pragma unroll
    for (int k0 = 0; k0 < KDIM; k0 += 32) {
        bf16x8 a = (bf16x8)(short)0;
        if (avalid) a = *(const bf16x8*)(ap + k0);
        #pragma unroll
        for (int nt = 0; nt < NTILES; ++nt) {
            bf16x8 b = *(const bf16x8*)&Bs[(nt * 16 + (lane & 15)) * LDB + k0 + (lane >> 4) * 8];
            acc[nt] = __builtin_amdgcn_mfma_f32_16x16x32_bf16(a, b, acc[nt], 0, 0, 0);
        }
    }
    #pragma unroll
    for (int j = 0; j < 4; ++j) {
        int row = r0 + (lane >> 4) * 4 + j;
        float pA = 0.f, pB = 0.f;
        #pragma unroll
        for (int nt = 0; nt < NTILES; ++nt) {
            int col = colbase + nt * 16 + (lane & 15);
            bool cok = col < ncols;
            float val = cok ? acc[nt][j] + bias[col] : 0.f;
            if (DOTMODE == 1) {
                float dv = dvec[col];
                if (nt < NTILES / 2) pA += val * dv; else pB += val * dv;
            } else if (DOTMODE == 2) {
                pA += cok ? val * dvec[col] : 0.f;
            }
            if (row < M && cok) out[(size_t)row * ldo + col] = f2bf(val);
        }
        if (DOTMODE) {
            pA += __shfl_xor(pA, 1);
            pA += __shfl_xor(pA, 2);
            pA += __shfl_xor(pA, 4);
            pA += __shfl_xor(pA, 8);
            if (DOTMODE == 1) {
                pB += __shfl_xor(pB, 1);
                pB += __shfl_xor(pB, 2);
                pB += __shfl_xor(pB, 4);
                pB += __shfl_xor(pB, 8);
            }
            if ((lane & 15) == 0 && row < M) {
                if (DOTMODE == 1) {
                    int hbase = blockIdx.y * 2;
                    int z = blockIdx.z;
                    dout[(size_t)(z * 4 + hbase) * M + row] = pA;
                    dout[(size_t)(z * 4 + hbase + 1) * M + row] = pB;
                } else {
                    dout[row] = pA;
                }
            }
        }
    }
}

// ---------------- node pass (layer 1): XCD-sliced, group-per-node, 3-slot pipeline ----------------
__global__ void k_node_pass1(const u16* __restrict__ Ycat, const float* __restrict__ se8,
                             const float* __restrict__ sv8, const int* __restrict__ start_v,
                             const int* __restrict__ deg_v, const int* __restrict__ csr_v_e,
                             u16* __restrict__ hbuf, int N, int E) {
    int bid = blockIdx.x;
    int s = bid & 7;
    int warp = threadIdx.x >> 6;
    int lane = threadIdx.x & 63;
    int g = lane >> 3, c = lane & 7;
    int node = (bid >> 3) * 32 + warp * 8 + g;
    if (node >= N) return;
    int p0 = start_v[node];
    int p1 = p0 + deg_v[node];
    float sv = sv8[(size_t)s * N + node];
    const float* seS = se8 + (size_t)s * E;
    const u16* ybase = Ycat + s * 64 + c * 8;
    float den = 0.f;
    float acc[8];
    #pragma unroll
    for (int j = 0; j < 8; ++j) acc[j] = 0.f;
    float sA = 0.f, sB = 0.f, sC = 0.f;
    u16x8 yA = {0}, yB = {0}, yC = {0};
#define NP1_LOAD(S, Y, IDX) { int e_ = csr_v_e[IDX]; S = seS[e_]; \
        Y = *(const u16x8*)(ybase + (size_t)e_ * 512); }
#define NP1_CONSUME(S, Y) { \
        float x_ = S + sv; x_ = fmaxf(x_, 0.2f * x_); float ex_ = __expf(x_); \
        den += ex_; \
        _Pragma("unroll") \
        for (int j = 0; j < 8; ++j) acc[j] += ex_ * bf2f(Y[j]); }
    int i = p0;
    if (i < p1) NP1_LOAD(sA, yA, i);
    if (i + 1 < p1) NP1_LOAD(sB, yB, i + 1);
    if (i + 2 < p1) NP1_LOAD(sC, yC, i + 2);
    for (; i + 2 < p1; i += 3) {
        NP1_CONSUME(sA, yA);
        if (i + 3 < p1) NP1_LOAD(sA, yA, i + 3);
        NP1_CONSUME(sB, yB);
        if (i + 4 < p1) NP1_LOAD(sB, yB, i + 4);
        NP1_CONSUME(sC, yC);
        if (i + 5 < p1) NP1_LOAD(sC, yC, i + 5);
    }
    if (i < p1) NP1_CONSUME(sA, yA);
    if (i + 1 < p1) NP1_CONSUME(sB, yB);
#undef NP1_LOAD
#undef NP1_CONSUME
    float inv = (p1 > p0) ? 1.f / den : 0.f;
    u16x8 r;
    #pragma unroll
    for (int j = 0; j < 8; ++j) {
        float o = acc[j] * inv;
        o = o > 0.f ? o : __expf(o) - 1.f;
        r[j] = f2bf(o);
    }
    *(u16x8*)(hbuf + (size_t)node * DCAT + s * 64 + c * 8) = r;
}

// ---------------- layer 2: group-per-segment, 2-slot pipelined ----------------

__global__ void k_edge_mean2(const u16* __restrict__ Xp2b, const int* __restrict__ start_e,
                             const int* __restrict__ deg_ea, const int* __restrict__ csr_e_v,
                             u16* __restrict__ Y2b, const float* __restrict__ ae2,
                             float* __restrict__ se2, int E) {
    int warp = threadIdx.x >> 6;
    int lane = threadIdx.x & 63;
    int g = lane >> 3, c = lane & 7;
    int edge = blockIdx.x * 32 + warp * 8 + g;
    if (edge >= E) return;
    int p0 = start_e[edge], p1 = p0 + deg_ea[edge];
    bool act = c < 5;
    const u16* xbase = Xp2b + c * 8;
    float acc[8];
    #pragma unroll
    for (int j = 0; j < 8; ++j) acc[j] = 0.f;
    u16x8 yA = {0}, yB = {0};
#define EM2_LOAD(Y, IDX) { int v_ = csr_e_v[IDX]; \
        if (act) Y = *(const u16x8*)(xbase + (size_t)v_ * NC); }
#define EM2_CONSUME(Y) { \
        _Pragma("unroll") \
        for (int j = 0; j < 8; ++j) acc[j] += bf2f(Y[j]); }
    int i = p0;
    if (i < p1) EM2_LOAD(yA, i);
    if (i + 1 < p1) EM2_LOAD(yB, i + 1);
    for (; i + 1 < p1; i += 2) {
        EM2_CONSUME(yA);
        if (i + 2 < p1) EM2_LOAD(yA, i + 2);
        EM2_CONSUME(yB);
        if (i + 3 < p1) EM2_LOAD(yB, i + 3);
    }
    if (i < p1) EM2_CONSUME(yA);
#undef EM2_LOAD
#undef EM2_CONSUME
    int deg = p1 - p0;
    float inv = 1.f / (float)(deg > 1 ? deg : 1);
    float p = 0.f;
    if (act) {
        u16x8 r;
        #pragma unroll
        for (int j = 0; j < 8; ++j) {
            float y = acc[j] * inv;
            p += y * ae2[c * 8 + j];
            r[j] = f2bf(y);
        }
        *(u16x8*)(Y2b + (size_t)edge * NC + c * 8) = r;
    }
    p += __shfl_xor(p, 1);
    p += __shfl_xor(p, 2);
    p += __shfl_xor(p, 4);
    if (c == 0) se2[edge] = p;
}

__global__ void k_node_pass2(const u16* __restrict__ Y2b, const float* __restrict__ se2,
                             const float* __restrict__ sv2, const int* __restrict__ start_v,
                             const int* __restrict__ deg_va, const int* __restrict__ csr_v_e,
                             float* __restrict__ out, int N) {
    int warp = threadIdx.x >> 6;
    int lane = threadIdx.x & 63;
    int g = lane >> 3, c = lane & 7;
    int node = blockIdx.x * 32 + warp * 8 + g;
    if (node >= N) return;
    int p0 = start_v[node], p1 = p0 + deg_va[node];
    bool act = c < 5;
    float* orow = out + (size_t)node * NC;
    if (p1 == p0) {
        if (act) {
            *(float4*)(orow + c * 8) = make_float4(0.f, 0.f, 0.f, 0.f);
            *(float4*)(orow + c * 8 + 4) = make_float4(0.f, 0.f, 0.f, 0.f);
        }
        return;
    }
    float svv = sv2[node];
    const u16* ybase = Y2b + c * 8;
    float den = 0.f;
    float acc[8];
    #pragma unroll
    for (int j = 0; j < 8; ++j) acc[j] = 0.f;
    float sA = 0.f, sB = 0.f;
    u16x8 yA = {0}, yB = {0};
#define NP2_LOAD(S, Y, IDX) { int e_ = csr_v_e[IDX]; S = se2[e_]; \
        if (act) Y = *(const u16x8*)(ybase + (size_t)e_ * NC); }
#define NP2_CONSUME(S, Y) { \
        float x_ = S + svv; x_ = fmaxf(x_, 0.2f * x_); float ex_ = __expf(x_); \
        den += ex_; \
        _Pragma("unroll") \
        for (int j = 0; j < 8; ++j) acc[j] += ex_ * bf2f(Y[j]); }
    int i = p0;
    if (i < p1) NP2_LOAD(sA, yA, i);
    if (i + 1 < p1) NP2_LOAD(sB, yB, i + 1);
    for (; i + 1 < p1; i += 2) {
        NP2_CONSUME(sA, yA);
        if (i + 2 < p1) NP2_LOAD(sA, yA, i + 2);
        NP2_CONSUME(sB, yB);
        if (i + 3 < p1) NP2_LOAD(sB, yB, i + 3);
    }
    if (i < p1) NP2_CONSUME(sA, yA);
#undef NP2_LOAD
#undef NP2_CONSUME
    if (act) {
        float inv = 1.f / den;
        float o[8];
        #pragma unroll
        for (int j = 0; j < 8; ++j) {
            float v = acc[j] * inv;
            o[j] = v > 0.f ? v : __expf(v) - 1.f;
        }
        *(float4*)(orow + c * 8) = make_float4(o[0], o[1], o[2], o[3]);
        *(float4*)(orow + c * 8 + 4) = make_float4(o[4], o[5], o[6], o[7]);
    }
}

// ---------------- launcher ----------------
extern "C" void kernel_launch(void* const* d_in, const int* in_sizes, int n_in,
                              void* d_out, int out_size, void* d_ws, size_t ws_size,
                              hipStream_t stream) {
    const float* x0 = (const float*)d_in[0];
    const float* x1 = (const float*)d_in[1];
    const float* W1 = (const float*)d_in[2];
    const float* b1 = (const float*)d_in[3];
    const float* ae1 = (const float*)d_in[4];
    const float* av1 = (const float*)d_in[5];
    const float* W2 = (const float*)d_in[6];
    const float* b2 = (const float*)d_in[7];
    const float* ae2 = (const float*)d_in[8];
    const float* av2 = (const float*)d_in[9];
    const int* pe = (const int*)d_in[10];
    const int* pv = (const int*)d_in[11];

    const int N = in_sizes[0] / DIN;  // 100000
    const int P = in_sizes[10];       // 1600000
    const int E = E_CONST;            // 20000
    const int NBKT_V = (N + SUBD_V - 1) / SUBD_V;   // 196
    const int NBKT_E = (E + SUBD_E - 1) / SUBD_E;   // 157

    char* base = (char*)d_ws;
    auto alloc = [&](size_t bytes) -> void* {
        void* p = (void*)base;
        base += (bytes + 255) & ~(size_t)255;
        return p;
    };
    u16* Xbi = (u16*)alloc((size_t)N * 256 * 2);
    u16* hbuf = (u16*)alloc((size_t)N * DCAT * 2);
    u16* Xbar0 = (u16*)alloc((size_t)E * DIN * 2);
    u16* Xbar1 = (u16*)alloc((size_t)E * DIN * 2);
    u16* Ycat = (u16*)alloc((size_t)E * 512 * 2);
    u16* Xp2b = (u16*)alloc((size_t)N * NC * 2);
    u16* Y2b = (u16*)alloc((size_t)E * NC * 2);
    float* se8 = (float*)alloc((size_t)8 * E * 4);
    float* se2 = (float*)alloc((size_t)E * 4);
    float* sv8 = (float*)alloc((size_t)8 * N * 4);
    float* sv2 = (float*)alloc((size_t)N * 4);
    float* wav = (float*)alloc((size_t)NH * DIN * 4);
    float* bav = (float*)alloc((size_t)NH * 4);
    u16* WcatT = (u16*)alloc((size_t)256 * DIN * 2);
    u16* W2T = (u16*)alloc((size_t)48 * DCAT * 2);
    uint2* sorted_v = (uint2*)alloc((size_t)P * 8);
    uint2* sorted_e = (uint2*)alloc((size_t)P * 8);
    int* start_v = (int*)alloc((size_t)N * 4);
    int* deg_v = (int*)alloc((size_t)N * 4);
    int* start_e = (int*)alloc((size_t)E * 4);
    int* deg_e = (int*)alloc((size_t)E * 4);
    int* csr_v_e = (int*)alloc((size_t)P * 4);
    int* csr_e_v = (int*)alloc((size_t)P * 4);
    char* zstart = base;
    int* bstart_v = (int*)alloc((size_t)(NBKT_V + 1) * 4);
    int* bstart_e = (int*)alloc((size_t)(NBKT_E + 1) * 4);
    int* cur_v = (int*)alloc((size_t)256 * 4);
    int* cur_e = (int*)alloc((size_t)256 * 4);
    size_t zbytes = (size_t)(base - zstart);

    if ((size_t)(base - (char*)d_ws) > ws_size) return;

    hipMemsetAsync(zstart, 0, zbytes, stream);

    dim3 b256(256);
    int nA = (P + CHUNKA - 1) / CHUNKA;   // 391
    k_hist2<<<nA, b256, 0, stream>>>(pv, pe, bstart_v, bstart_e, P);
    k_scan_both<<<2, 1024, 0, stream>>>(bstart_v, NBKT_V, bstart_e, NBKT_E);
    k_scatter2way<<<nA, b256, 0, stream>>>(pv, pe, bstart_v, bstart_e, cur_v, cur_e,
                                           sorted_v, sorted_e, P);
    k_build_ord<SUBD_V, SH_V, NSUB_E, ECH><<<NBKT_V, b256, 0, stream>>>(sorted_v, bstart_v,
                                                                        start_v, deg_v,
                                                                        csr_v_e, N);
    k_build_ord<SUBD_E, SH_E, NSUB_V, VCH><<<NBKT_E, b256, 0, stream>>>(sorted_e, bstart_e,
                                                                        start_e, deg_e,
                                                                        csr_e_v, E);

    k_prep<<<228, b256, 0, stream>>>(W1, b1, av1, W2, wav, bav, WcatT, W2T);

    int gN4 = (N + 3) / 4;
    int gE4 = (E + 3) / 4;
    dim3 gconv(gN4, 2);
    k_conv<<<gconv, b256, 0, stream>>>(x0, x1, wav, bav, Xbi, sv8, N);

    k_edge_mean1<<<gE4, b256, 0, stream>>>(Xbi, start_e, deg_e, csr_e_v, Xbar0, Xbar1, E);
    dim3 g1((E + 63) / 64, 2, 2);
    k_gemm_mfma<DIN, 8, 1><<<g1, b256, 0, stream>>>(Xbar0, Xbar1, E, WcatT, b1,
                                                    Ycat, Ycat + 256, 512, 256, ae1, se8);
    int gnp1 = ((N + 31) / 32) * 8;
    k_node_pass1<<<gnp1, b256, 0, stream>>>(Ycat, se8, sv8, start_v, deg_v, csr_v_e,
                                            hbuf, N, E);

    dim3 g2((N + 63) / 64, 1, 1);
    k_gemm_mfma<DCAT, 3, 2><<<g2, b256, 0, stream>>>(hbuf, hbuf, N, W2T, b2, Xp2b, Xp2b,
                                                     NC, NC, av2, sv2);
    int gseg = (E + 31) / 32;
    k_edge_mean2<<<gseg, b256, 0, stream>>>(Xp2b, start_e, deg_e, csr_e_v, Y2b, ae2, se2, E);
    int gnp2 = (N + 31) / 32;
    k_node_pass2<<<gnp2, b256, 0, stream>>>(Y2b, se2, sv2, start_v, deg_v, csr_v_e,
                                            (float*)d_out, N);
}